// Round 1
// baseline (963.410 us; speedup 1.0000x reference)
//
#include <hip/hip_runtime.h>

// out = (fftn(x, axes=all).real + imag) / numel  -- the spectral branch of the
// reference is dead code. 4D FFT over (B=16, C=64, H=256, W=256), separable.
// Half-spectrum storage along W (129 cols, padded to 132) via Hermitian symmetry.

#define NB 16
#define NC 64
#define NH 256
#define NW 256
#define WP 132           // padded complex line length along kw (129 used)
#define CSTRIDE (NH*WP)  // c stride in complex elements
#define BSTRIDE (NC*NH*WP)

__device__ __forceinline__ float2 cadd(float2 a, float2 b){ return make_float2(a.x+b.x, a.y+b.y); }
__device__ __forceinline__ float2 csub(float2 a, float2 b){ return make_float2(a.x-b.x, a.y-b.y); }
__device__ __forceinline__ float2 cmul(float2 a, float2 b){ return make_float2(a.x*b.x - a.y*b.y, a.x*b.y + a.y*b.x); }

// e^{-2*pi*i * frac}
__device__ __forceinline__ float2 twd(float frac){
  float sn, cs;
  __sincosf(-6.28318530717958647692f * frac, &sn, &cs);
  return make_float2(cs, sn);
}

// 4-point DFT, natural order in/out
__device__ __forceinline__ void dft4(float2&a,float2&b,float2&c,float2&d){
  float2 t0=cadd(a,c), t1=csub(a,c), t2=cadd(b,d), t3=csub(b,d);
  float2 t3i = make_float2(t3.y, -t3.x);   // -i * t3
  a=cadd(t0,t2); c=csub(t0,t2); b=cadd(t1,t3i); d=csub(t1,t3i);
}

// 8-point FFT, natural order in/out (DIT radix-2 over two DFT4)
__device__ __forceinline__ void fft8(float2 v[8]){
  float2 e0=v[0],e1=v[2],e2=v[4],e3=v[6];
  float2 o0=v[1],o1=v[3],o2=v[5],o3=v[7];
  dft4(e0,e1,e2,e3); dft4(o0,o1,o2,o3);
  const float s=0.70710678118654752440f;
  float2 w1o=make_float2(s*(o1.x+o1.y), s*(o1.y-o1.x));   // e^{-i pi/4} * o1
  float2 w2o=make_float2(o2.y, -o2.x);                    // -i * o2
  float2 w3o=make_float2(s*(o3.y-o3.x), -s*(o3.x+o3.y));  // e^{-i 3pi/4} * o3
  v[0]=cadd(e0,o0); v[4]=csub(e0,o0);
  v[1]=cadd(e1,w1o); v[5]=csub(e1,w1o);
  v[2]=cadd(e2,w2o); v[6]=csub(e2,w2o);
  v[3]=cadd(e3,w3o); v[7]=csub(e3,w3o);
}

// 16-point FFT, natural order in/out (DIT radix-2 over two FFT8)
__device__ __forceinline__ void fft16(float2 v[16]){
  float2 e[8], o[8];
#pragma unroll
  for(int i=0;i<8;i++){ e[i]=v[2*i]; o[i]=v[2*i+1]; }
  fft8(e); fft8(o);
  const float c1=0.92387953251128675613f, s1=0.38268343236508977173f, s=0.70710678118654752440f;
  const float wr[8] = {1.f,  c1,  s,  s1, 0.f, -s1, -s, -c1};
  const float wi[8] = {0.f, -s1, -s, -c1, -1.f, -c1, -s, -s1};
#pragma unroll
  for(int k=0;k<8;k++){
    float2 wo = make_float2(wr[k]*o[k].x - wi[k]*o[k].y, wr[k]*o[k].y + wi[k]*o[k].x);
    v[k]=cadd(e[k],wo); v[k+8]=csub(e[k],wo);
  }
}

// ---------------- K1: real 256-pt FFT along W, store kw<=128 ----------------
// 16 lines/wg; tid&15 = j (position-in-line, n2), tid>>4 = local line (h).
__global__ __launch_bounds__(256) void k1_fftW(const float* __restrict__ x, float2* __restrict__ S){
  __shared__ float2 lds[16][16][17];
  const int j    = threadIdx.x & 15;
  const int line = threadIdx.x >> 4;
  const int gline = blockIdx.x * 16 + line;   // (b*64+c)*256 + h, 0..262143
  const float* px = x + (size_t)gline * NW;
  float2 v[16];
#pragma unroll
  for(int n1=0;n1<16;n1++) v[n1] = make_float2(px[16*n1 + j], 0.f);
  fft16(v);                                   // inner DFT over n1, index k1
#pragma unroll
  for(int k1=0;k1<16;k1++){
    v[k1] = cmul(v[k1], twd((float)(j*k1) * (1.0f/256.0f)));
    lds[line][k1][j] = v[k1];
  }
  __syncthreads();
  float2 u[16];
#pragma unroll
  for(int n2=0;n2<16;n2++) u[n2] = lds[line][j][n2];
  fft16(u);                                   // outer DFT over n2, index k2
  float2* ps = S + (size_t)gline * WP;        // X[j + 16*k2]
#pragma unroll
  for(int k2=0;k2<8;k2++) ps[j + 16*k2] = u[k2];
  if(j==0) ps[128] = u[8];
}

// ---------------- K2: in-place complex 256-pt FFT along H -------------------
// 16 kw columns/wg; tid&15 = kw offset (line id), tid>>4 = j.
__global__ __launch_bounds__(256) void k2_fftH(float2* __restrict__ S){
  __shared__ float2 lds[16][16][17];
  const int kwo  = threadIdx.x & 15;
  const int j    = threadIdx.x >> 4;
  const int tile = blockIdx.x % 9;
  const int slice= blockIdx.x / 9;            // b*64+c
  const int kw   = tile*16 + kwo;
  const bool act = (kw <= 128);
  float2* base = S + (size_t)slice * NH * WP + kw;
  float2 v[16];
#pragma unroll
  for(int n1=0;n1<16;n1++) v[n1] = act ? base[(16*n1 + j) * WP] : make_float2(0.f,0.f);
  fft16(v);
#pragma unroll
  for(int k1=0;k1<16;k1++){
    v[k1] = cmul(v[k1], twd((float)(j*k1) * (1.0f/256.0f)));
    lds[kwo][k1][j] = v[k1];
  }
  __syncthreads();
  float2 u[16];
#pragma unroll
  for(int n2=0;n2<16;n2++) u[n2] = lds[kwo][j][n2];
  fft16(u);
  if(act){
#pragma unroll
    for(int k2=0;k2<16;k2++) base[(j + 16*k2) * WP] = u[k2];
  }
}

// ---------------- K3: in-place complex 64-pt FFT along C --------------------
// 32 kw columns/wg; tid&31 = kw offset, tid>>5 = j (8 threads/line).
__global__ __launch_bounds__(256) void k3_fftC(float2* __restrict__ S){
  __shared__ float2 lds[32][8][9];
  const int kwo  = threadIdx.x & 31;
  const int j    = threadIdx.x >> 5;
  const int tile = blockIdx.x % 5;
  const int bh   = blockIdx.x / 5;            // b*256 + h
  const int b = bh >> 8, h = bh & 255;
  const int kw = tile*32 + kwo;
  const bool act = (kw <= 128);
  float2* base = S + (size_t)b * BSTRIDE + (size_t)h * WP + kw;
  float2 v[8];
#pragma unroll
  for(int n1=0;n1<8;n1++) v[n1] = act ? base[(8*n1 + j) * CSTRIDE] : make_float2(0.f,0.f);
  fft8(v);
#pragma unroll
  for(int k1=0;k1<8;k1++){
    v[k1] = cmul(v[k1], twd((float)(j*k1) * (1.0f/64.0f)));
    lds[kwo][k1][j] = v[k1];
  }
  __syncthreads();
  float2 u[8];
#pragma unroll
  for(int n2=0;n2<8;n2++) u[n2] = lds[kwo][j][n2];
  fft8(u);
  if(act){
#pragma unroll
    for(int k2=0;k2<8;k2++) base[(j + 8*k2) * CSTRIDE] = u[k2];
  }
}

// ---------------- K4: in-place complex 16-pt FFT along B, 1 thread/line ----
__global__ __launch_bounds__(256) void k4_fftB(float2* __restrict__ S){
  const int idx = blockIdx.x * 256 + threadIdx.x;   // over (c,h,kwp)
  const int kw = idx % WP;
  const int hc = idx / WP;
  const int h = hc & 255, c = hc >> 8;
  if(kw > 128 || c >= NC) return;
  float2* base = S + (size_t)c * CSTRIDE + (size_t)h * WP + kw;
  float2 v[16];
#pragma unroll
  for(int b=0;b<16;b++) v[b] = base[(size_t)b * BSTRIDE];
  fft16(v);
#pragma unroll
  for(int b=0;b<16;b++) base[(size_t)b * BSTRIDE] = v[b];
}

// ---------------- K5: out = (Re+Im)/N with Hermitian reconstruction ---------
__global__ __launch_bounds__(256) void k5_final(const float2* __restrict__ S, float* __restrict__ out){
  const int idx = blockIdx.x * 256 + threadIdx.x;   // 0..2^26-1
  const int w = idx & 255;
  const int h = (idx >> 8) & 255;
  const int c = (idx >> 16) & 63;
  const int b = idx >> 22;
  const float inv = 1.0f / 67108864.0f;
  float val;
  if(w <= 128){
    float2 z = S[((size_t)(b*NC + c) * NH + h) * WP + w];
    val = (z.x + z.y) * inv;
  } else {
    const int p  = 256 - w;
    const int b2 = (16 - b) & 15;
    const int c2 = (64 - c) & 63;
    const int h2 = (256 - h) & 255;
    float2 z = S[((size_t)(b2*NC + c2) * NH + h2) * WP + p];
    val = (z.x - z.y) * inv;      // conj: Re + Im(conj) = Re - Im
  }
  out[idx] = val;
}

extern "C" void kernel_launch(void* const* d_in, const int* in_sizes, int n_in,
                              void* d_out, int out_size, void* d_ws, size_t ws_size,
                              hipStream_t stream) {
  const float* x = (const float*)d_in[0];   // (16,64,256,256) fp32
  // d_in[1], d_in[2] (weights) and d_in[3] (error_estimate) are dead code in the reference.
  float* out = (float*)d_out;               // (16,64,256,256) fp32
  float2* S  = (float2*)d_ws;               // needs 16*64*256*132*8 = ~264 MiB

  k1_fftW<<<NB*NC*NH/16, 256, 0, stream>>>(x, S);        // 16384 blocks
  k2_fftH<<<NB*NC*9,     256, 0, stream>>>(S);           // 9216 blocks
  k3_fftC<<<NB*NH*5,     256, 0, stream>>>(S);           // 20480 blocks
  k4_fftB<<<(NC*NH*WP+255)/256, 256, 0, stream>>>(S);    // 8448 blocks
  k5_final<<<(NB*NC*NH*NW)/256, 256, 0, stream>>>(S, out); // 262144 blocks
}

// Round 2
// 909.118 us; speedup vs baseline: 1.0597x; 1.0597x over previous
//
#include <hip/hip_runtime.h>

// out = (fftn(x, axes=all).real + imag) / numel  -- the spectral branch of the
// reference is dead code. 4D FFT over (B=16, C=64, H=256, W=256), separable.
// 3 passes:
//   K1: real 256-pt FFT along W (half-spectrum, kw<=128, padded to WP)
//   K2: complex 256-pt FFT along H (in place)
//   K3: fused 64-pt FFT along C + 16-pt FFT along B + (Re+/-Im)/N finalize,
//       writing d_out directly (direct + Hermitian-mirror columns).

#define NB 16
#define NC 64
#define NH 256
#define NW 256
#define WP 132           // padded complex line length along kw (129 used)
#define CSTRIDE (NH*WP)  // c stride in complex elements
#define BSTRIDE (NC*NH*WP)
#define LSTRIDE (NH*WP)  // stride between consecutive (b*64+c) lines

__device__ __forceinline__ float2 cadd(float2 a, float2 b){ return make_float2(a.x+b.x, a.y+b.y); }
__device__ __forceinline__ float2 csub(float2 a, float2 b){ return make_float2(a.x-b.x, a.y-b.y); }
__device__ __forceinline__ float2 cmul(float2 a, float2 b){ return make_float2(a.x*b.x - a.y*b.y, a.x*b.y + a.y*b.x); }

// e^{-2*pi*i * frac}
__device__ __forceinline__ float2 twd(float frac){
  float sn, cs;
  __sincosf(-6.28318530717958647692f * frac, &sn, &cs);
  return make_float2(cs, sn);
}

// 4-point DFT, natural order in/out
__device__ __forceinline__ void dft4(float2&a,float2&b,float2&c,float2&d){
  float2 t0=cadd(a,c), t1=csub(a,c), t2=cadd(b,d), t3=csub(b,d);
  float2 t3i = make_float2(t3.y, -t3.x);   // -i * t3
  a=cadd(t0,t2); c=csub(t0,t2); b=cadd(t1,t3i); d=csub(t1,t3i);
}

// 8-point FFT, natural order in/out (DIT radix-2 over two DFT4)
__device__ __forceinline__ void fft8(float2 v[8]){
  float2 e0=v[0],e1=v[2],e2=v[4],e3=v[6];
  float2 o0=v[1],o1=v[3],o2=v[5],o3=v[7];
  dft4(e0,e1,e2,e3); dft4(o0,o1,o2,o3);
  const float s=0.70710678118654752440f;
  float2 w1o=make_float2(s*(o1.x+o1.y), s*(o1.y-o1.x));   // e^{-i pi/4} * o1
  float2 w2o=make_float2(o2.y, -o2.x);                    // -i * o2
  float2 w3o=make_float2(s*(o3.y-o3.x), -s*(o3.x+o3.y));  // e^{-i 3pi/4} * o3
  v[0]=cadd(e0,o0); v[4]=csub(e0,o0);
  v[1]=cadd(e1,w1o); v[5]=csub(e1,w1o);
  v[2]=cadd(e2,w2o); v[6]=csub(e2,w2o);
  v[3]=cadd(e3,w3o); v[7]=csub(e3,w3o);
}

// 16-point FFT, natural order in/out (DIT radix-2 over two FFT8)
__device__ __forceinline__ void fft16(float2 v[16]){
  float2 e[8], o[8];
#pragma unroll
  for(int i=0;i<8;i++){ e[i]=v[2*i]; o[i]=v[2*i+1]; }
  fft8(e); fft8(o);
  const float c1=0.92387953251128675613f, s1=0.38268343236508977173f, s=0.70710678118654752440f;
  const float wr[8] = {1.f,  c1,  s,  s1, 0.f, -s1, -s, -c1};
  const float wi[8] = {0.f, -s1, -s, -c1, -1.f, -c1, -s, -s1};
#pragma unroll
  for(int k=0;k<8;k++){
    float2 wo = make_float2(wr[k]*o[k].x - wi[k]*o[k].y, wr[k]*o[k].y + wi[k]*o[k].x);
    v[k]=cadd(e[k],wo); v[k+8]=csub(e[k],wo);
  }
}

// ---------------- K1: real 256-pt FFT along W, store kw<=128 ----------------
// 16 lines/wg; tid&15 = j (position-in-line, n2), tid>>4 = local line (h).
__global__ __launch_bounds__(256) void k1_fftW(const float* __restrict__ x, float2* __restrict__ S){
  __shared__ float2 lds[16][16][17];
  const int j    = threadIdx.x & 15;
  const int line = threadIdx.x >> 4;
  const int gline = blockIdx.x * 16 + line;   // (b*64+c)*256 + h, 0..262143
  const float* px = x + (size_t)gline * NW;
  float2 v[16];
#pragma unroll
  for(int n1=0;n1<16;n1++) v[n1] = make_float2(px[16*n1 + j], 0.f);
  fft16(v);                                   // inner DFT over n1, index k1
#pragma unroll
  for(int k1=0;k1<16;k1++){
    v[k1] = cmul(v[k1], twd((float)(j*k1) * (1.0f/256.0f)));
    lds[line][k1][j] = v[k1];
  }
  __syncthreads();
  float2 u[16];
#pragma unroll
  for(int n2=0;n2<16;n2++) u[n2] = lds[line][j][n2];
  fft16(u);                                   // outer DFT over n2, index k2
  float2* ps = S + (size_t)gline * WP;        // X[j + 16*k2]
#pragma unroll
  for(int k2=0;k2<8;k2++) ps[j + 16*k2] = u[k2];
  if(j==0) ps[128] = u[8];
}

// ---------------- K2: in-place complex 256-pt FFT along H -------------------
// 16 kw columns/wg; tid&15 = kw offset (line id), tid>>4 = j.
__global__ __launch_bounds__(256) void k2_fftH(float2* __restrict__ S){
  __shared__ float2 lds[16][16][17];
  const int kwo  = threadIdx.x & 15;
  const int j    = threadIdx.x >> 4;
  const int tile = blockIdx.x % 9;
  const int slice= blockIdx.x / 9;            // b*64+c
  const int kw   = tile*16 + kwo;
  const bool act = (kw <= 128);
  float2* base = S + (size_t)slice * NH * WP + kw;
  float2 v[16];
#pragma unroll
  for(int n1=0;n1<16;n1++) v[n1] = act ? base[(16*n1 + j) * WP] : make_float2(0.f,0.f);
  fft16(v);
#pragma unroll
  for(int k1=0;k1<16;k1++){
    v[k1] = cmul(v[k1], twd((float)(j*k1) * (1.0f/256.0f)));
    lds[kwo][k1][j] = v[k1];
  }
  __syncthreads();
  float2 u[16];
#pragma unroll
  for(int n2=0;n2<16;n2++) u[n2] = lds[kwo][j][n2];
  fft16(u);
  if(act){
#pragma unroll
    for(int k2=0;k2<16;k2++) base[(j + 16*k2) * WP] = u[k2];
  }
}

// ------- K3: fused C-FFT(64) + B-FFT(16) + finalize, writes d_out -----------
// Workgroup: fixed h, tile of 8 kw, all (b,c). LDS A[1024][8(+1)] complex.
// blockIdx.x = tile*256 + h; tiles 0..16 (tile 16 covers kw=128 only).
__global__ __launch_bounds__(256) void k3_fused(const float2* __restrict__ S, float* __restrict__ out){
  __shared__ float2 A[1024][9];               // 72 KB, [bc][kwo]
  const int t    = threadIdx.x;
  const int h    = blockIdx.x & 255;
  const int tile = blockIdx.x >> 8;           // 0..16
  const int kw0  = tile * 8;
  const float2* Sbase = S + (size_t)h * WP + kw0;

  // ---- load: 1024 lines x 8 complex (= 4 float4 per line) ----
#pragma unroll
  for(int r=0;r<16;r++){
    int f    = t + 256*r;                     // 0..4095
    int line = f >> 2;                        // bc = b*64+c
    int part = f & 3;                         // which float4 (2 complex)
    float4 val;
    if(kw0 + part*2 + 1 < WP){
      val = *(const float4*)(Sbase + (size_t)line * LSTRIDE + part*2);
    } else {
      val = make_float4(0.f,0.f,0.f,0.f);     // tile 16 tail, never used
    }
    A[line][part*2]     = make_float2(val.x, val.y);
    A[line][part*2 + 1] = make_float2(val.z, val.w);
  }
  __syncthreads();

  // ---- stage C1: 8-pt FFT over n1 (c = 8*n1 + n2), twiddle ----
  // items (b, kwo, n2): read/write set private per item -> no barrier inside.
#pragma unroll
  for(int q=0;q<4;q++){
    int item = t + 256*q;
    int kwo = item & 7, n2 = (item>>3) & 7, b = item >> 6;
    float2 v[8];
#pragma unroll
    for(int n1=0;n1<8;n1++) v[n1] = A[b*64 + 8*n1 + n2][kwo];
    fft8(v);                                  // -> k1
#pragma unroll
    for(int k1=0;k1<8;k1++) A[b*64 + 8*k1 + n2][kwo] = cmul(v[k1], twd((float)(n2*k1) * (1.0f/64.0f)));
  }
  __syncthreads();

  // ---- stage C2: 8-pt FFT over n2 for fixed k1; c-freq kc = k1 + 8*k2 ----
  // cross-item write hazard -> read all, sync, write all.
  {
    float2 u[4][8];
#pragma unroll
    for(int q=0;q<4;q++){
      int item = t + 256*q;
      int kwo = item & 7, k1 = (item>>3) & 7, b = item >> 6;
#pragma unroll
      for(int n2=0;n2<8;n2++) u[q][n2] = A[b*64 + 8*k1 + n2][kwo];
      fft8(u[q]);                             // -> k2
    }
    __syncthreads();
#pragma unroll
    for(int q=0;q<4;q++){
      int item = t + 256*q;
      int kwo = item & 7, k1 = (item>>3) & 7, b = item >> 6;
#pragma unroll
      for(int k2=0;k2<8;k2++) A[b*64 + (k1 + 8*k2)][kwo] = u[q][k2];
    }
  }
  __syncthreads();

  // ---- stage B: 16-pt FFT over b, then finalize writes ----
  const float inv = 1.0f / 67108864.0f;
  const int h2 = (NH - h) & 255;
#pragma unroll
  for(int q=0;q<2;q++){
    int item = t + 256*q;
    int kwo = item & 7, kc = item >> 3;       // kc 0..63
    float2 v[16];
#pragma unroll
    for(int b=0;b<16;b++) v[b] = A[b*64 + kc][kwo];
    fft16(v);                                 // -> kb
    const int kw = kw0 + kwo;
    if(kw <= 128){
      const int kc2 = (NC - kc) & 63;
#pragma unroll
      for(int kb=0;kb<16;kb++){
        float2 z = v[kb];
        out[(((size_t)kb*NC + kc)*NH + h)*NW + kw] = (z.x + z.y) * inv;
        if(kw >= 1 && kw <= 127){
          const int kb2 = (16 - kb) & 15;
          out[(((size_t)kb2*NC + kc2)*NH + h2)*NW + (NW - kw)] = (z.x - z.y) * inv;
        }
      }
    }
  }
}

extern "C" void kernel_launch(void* const* d_in, const int* in_sizes, int n_in,
                              void* d_out, int out_size, void* d_ws, size_t ws_size,
                              hipStream_t stream) {
  const float* x = (const float*)d_in[0];   // (16,64,256,256) fp32
  // d_in[1], d_in[2] (weights) and d_in[3] (error_estimate) are dead code.
  float* out = (float*)d_out;               // (16,64,256,256) fp32
  float2* S  = (float2*)d_ws;               // 16*64*256*132*8 = ~264 MiB

  k1_fftW<<<NB*NC*NH/16, 256, 0, stream>>>(x, S);        // 16384 blocks
  k2_fftH<<<NB*NC*9,     256, 0, stream>>>(S);           // 9216 blocks
  k3_fused<<<17*256,     256, 0, stream>>>(S, out);      // 4352 blocks
}